// Round 18
// baseline (302.007 us; speedup 1.0000x reference)
//
#include <hip/hip_runtime.h>
#include <stdint.h>

// Problem constants (Gemma3 attention block)
#define T_TOK 4096
#define DM    2560
#define NQ    8
#define NKV   4
#define HD    256
#define WIN   1024

using bf16x8 = __attribute__((ext_vector_type(8))) short;
using f32x4  = __attribute__((ext_vector_type(4))) float;
typedef unsigned short u16;

__device__ __forceinline__ u16 f2bf(float x) {
  union { float f; uint32_t u; } v; v.f = x;
  uint32_t u = v.u;
  return (u16)((u + 0x7fffu + ((u >> 16) & 1u)) >> 16);  // RNE
}
__device__ __forceinline__ float bf2f(u16 b) {
  union { uint32_t u; float f; } v; v.u = ((uint32_t)b) << 16;
  return v.f;
}

// async global->LDS, 16B per lane. LDS dest is wave-uniform base; HW adds lane*16.
__device__ __forceinline__ void async_cp16(const void* g, void* lds) {
  __builtin_amdgcn_global_load_lds(
      (const __attribute__((address_space(1))) uint32_t*)(uintptr_t)g,
      (__attribute__((address_space(3))) uint32_t*)(uint32_t)(uintptr_t)lds,
      16, 0, 0);
}

// ---------------------------------------------------------------------------
// Fused prelude: one launch covering x->bf16 convert + 4 weight transposes.
__global__ __launch_bounds__(256) void prelude(
    const float* __restrict__ x,  const float* __restrict__ wq,
    const float* __restrict__ wk, const float* __restrict__ wv,
    const float* __restrict__ wo,
    u16* __restrict__ xb, u16* __restrict__ wqkvT, u16* __restrict__ woT)
{
  __shared__ u16 tile[64][72];
  const int bid0 = blockIdx.x;

  if (bid0 < 1024) {
    for (int i = (bid0 * 256 + threadIdx.x) * 8; i < T_TOK * DM; i += 1024 * 256 * 8) {
      float4 a = *(const float4*)(x + i);
      float4 b = *(const float4*)(x + i + 4);
      bf16x8 o;
      o[0] = (short)f2bf(a.x); o[1] = (short)f2bf(a.y);
      o[2] = (short)f2bf(a.z); o[3] = (short)f2bf(a.w);
      o[4] = (short)f2bf(b.x); o[5] = (short)f2bf(b.y);
      o[6] = (short)f2bf(b.z); o[7] = (short)f2bf(b.w);
      *(bf16x8*)(xb + i) = o;
    }
    return;
  }

  const float* src; u16* dst; int R, C, bx, by;
  if (bid0 < 2304)      { int b = bid0 - 1024; src = wq; dst = wqkvT;             R = DM;   C = 2048; bx = b & 31; by = b >> 5; }
  else if (bid0 < 2944) { int b = bid0 - 2304; src = wk; dst = wqkvT + 2048 * DM; R = DM;   C = 1024; bx = b & 15; by = b >> 4; }
  else if (bid0 < 3584) { int b = bid0 - 2944; src = wv; dst = wqkvT + 3072 * DM; R = DM;   C = 1024; bx = b & 15; by = b >> 4; }
  else                  { int b = bid0 - 3584; src = wo; dst = woT;               R = 2048; C = DM;   bx = b % 40; by = b / 40; }

  const int r0 = by * 64, c0 = bx * 64;
  const int tr = threadIdx.x >> 6, tc = threadIdx.x & 63;
  #pragma unroll
  for (int i = 0; i < 16; ++i) {
    int r = tr + i * 4;
    tile[r][tc] = f2bf(src[(size_t)(r0 + r) * C + c0 + tc]);
  }
  __syncthreads();
  const int oc = threadIdx.x >> 3, ch = threadIdx.x & 7;
  #pragma unroll
  for (int h = 0; h < 2; ++h) {
    const int c = oc + h * 32;
    bf16x8 v;
    #pragma unroll
    for (int j = 0; j < 8; ++j) v[j] = (short)tile[ch * 8 + j][c];
    *(bf16x8*)(dst + (size_t)(c0 + c) * R + r0 + ch * 8) = v;
  }
}

// ---------------------------------------------------------------------------
// QKV GEMM (256x256 tile, r12-verified progressive schedule) with FUSED
// epilogue: RMSNorm + q-scale + RoPE + scatter to q_b / kv cache.
// Each block's 256-col n-group is exactly one head slot: g<8 q, 8..11 k,
// 12..15 v. Row reductions are block-local; RoPE pair exchange (h <-> h+128)
// goes through a 128KB f32 LDS alias of the (dead) staging buffer.
__global__ __launch_bounds__(512, 1) void gemm_qkv(
    const u16* __restrict__ A, const u16* __restrict__ B,
    const float* __restrict__ qnw, const float* __restrict__ knw,
    const int* __restrict__ pos,
    u16* __restrict__ qb, u16* __restrict__ kb, u16* __restrict__ vb,
    float* __restrict__ kvout, int Kd, int lda, int ldb)
{
  __shared__ __align__(16) u16 lds[2][2][256 * 64];  // [buf][A|B] 128 KiB
  __shared__ float partial[4][256];
  __shared__ float scl[256];
  const int tid = threadIdx.x;
  const int wave = tid >> 6, lane = tid & 63;
  const int lg = lane >> 4, lc = lane & 15;
  const int wr = wave >> 2, wc = wave & 3;  // 2 x 4 wave grid
  const int nwg = gridDim.x, bid = blockIdx.x;
  const int nid = (bid & 7) * (nwg >> 3) + (bid >> 3);
  const int m0 = (nid & 15) * 256, n0 = (nid >> 4) * 256;
  const int NT = Kd >> 6;

  const int srow = tid >> 3;
  const int scol = ((tid & 7) * 16) ^ ((srow & 7) << 4);
  const u16* Ag = A + (size_t)(m0 + srow) * lda + (scol >> 1);
  const u16* Bg = B + (size_t)(n0 + srow) * ldb + (scol >> 1);

  #define STAGE_B4(BUF, KT) do {                                              \
    const int kc_ = (KT) * 64;                                                \
    _Pragma("unroll")                                                         \
    for (int li = 0; li < 4; ++li)                                            \
      async_cp16(Bg + (size_t)(li * 64) * ldb + kc_,                          \
                 (char*)&lds[BUF][1][0] + li * 8192 + wave * 1024);           \
  } while (0)
  #define STAGE_A2(BUF, KT, H) do {                                           \
    const int kc_ = (KT) * 64;                                                \
    async_cp16(Ag + (size_t)((H) * 64) * lda + kc_,                           \
               (char*)&lds[BUF][0][0] + (H) * 8192 + wave * 1024);            \
    async_cp16(Ag + (size_t)((H) * 64 + 128) * lda + kc_,                     \
               (char*)&lds[BUF][0][0] + ((H) + 2) * 8192 + wave * 1024);      \
  } while (0)
  #define LOAD_AF(P) do {                                                     \
    _Pragma("unroll")                                                         \
    for (int im = 0; im < 2; ++im)                                            \
      _Pragma("unroll")                                                       \
      for (int k2 = 0; k2 < 2; ++k2) {                                        \
        const int row = wr * 128 + ((P) * 2 + im) * 16 + lc;                  \
        const int cb = k2 * 64 + lg * 16;                                     \
        af[im][k2] = *(const bf16x8*)(Ab + row * 128 + (cb ^ ((row & 7) << 4))); \
      }                                                                       \
  } while (0)
  #define MFMA_Q(P) do {                                                      \
    __builtin_amdgcn_s_setprio(1);                                            \
    _Pragma("unroll")                                                         \
    for (int im = 0; im < 2; ++im)                                            \
      _Pragma("unroll")                                                       \
      for (int j = 0; j < 4; ++j)                                             \
        _Pragma("unroll")                                                     \
        for (int k2 = 0; k2 < 2; ++k2)                                        \
          acc[(P) * 2 + im][j] = __builtin_amdgcn_mfma_f32_16x16x32_bf16(     \
              af[im][k2], bfr[j][k2], acc[(P) * 2 + im][j], 0, 0, 0);         \
    __builtin_amdgcn_s_setprio(0);                                            \
  } while (0)
  #define LGKM0_BAR() do {                                                    \
    asm volatile("s_waitcnt lgkmcnt(0)" ::: "memory");                        \
    __builtin_amdgcn_s_barrier();                                             \
    __builtin_amdgcn_sched_barrier(0);                                        \
  } while (0)

  const f32x4 zf = {0.f, 0.f, 0.f, 0.f};
  f32x4 acc[8][4];
  #pragma unroll
  for (int i = 0; i < 8; ++i)
    #pragma unroll
    for (int j = 0; j < 4; ++j) acc[i][j] = zf;

  STAGE_B4(0, 0); STAGE_A2(0, 0, 0); STAGE_A2(0, 0, 1);
  STAGE_B4(1, 1); STAGE_A2(1, 1, 0); STAGE_A2(1, 1, 1);
  asm volatile("s_waitcnt vmcnt(8)" ::: "memory");
  __builtin_amdgcn_s_barrier();
  __builtin_amdgcn_sched_barrier(0);

  for (int t = 0; t < NT; ++t) {
    const int cur = t & 1;
    const char* Ab = (const char*)&lds[cur][0][0];
    const char* Bb = (const char*)&lds[cur][1][0];
    int nk = t + 2; if (nk > NT - 1) nk = NT - 1;

    bf16x8 bfr[4][2], af[2][2];
    #pragma unroll
    for (int j = 0; j < 4; ++j)
      #pragma unroll
      for (int k2 = 0; k2 < 2; ++k2) {
        const int row = wc * 64 + j * 16 + lc;
        const int cb = k2 * 64 + lg * 16;
        bfr[j][k2] = *(const bf16x8*)(Bb + row * 128 + (cb ^ ((row & 7) << 4)));
      }
    LOAD_AF(0);
    LGKM0_BAR();
    STAGE_B4(cur, nk);
    MFMA_Q(0);
    LOAD_AF(1);
    LGKM0_BAR();
    STAGE_A2(cur, nk, 0);
    MFMA_Q(1);
    LOAD_AF(2);
    MFMA_Q(2);
    LOAD_AF(3);
    LGKM0_BAR();
    STAGE_A2(cur, nk, 1);
    MFMA_Q(3);
    asm volatile("s_waitcnt vmcnt(8)" ::: "memory");
    __builtin_amdgcn_s_barrier();
    __builtin_amdgcn_sched_barrier(0);
  }
  #undef STAGE_B4
  #undef STAGE_A2
  #undef LOAD_AF
  #undef MFMA_Q
  #undef LGKM0_BAR

  // ================= fused epilogue =================
  const int g = nid >> 4;  // head slot 0..15

  if (g >= 12) {
    // ---- V: raw values -> f32 kv cache + bf16 copy
    const int kkh = g - 12;
    #pragma unroll
    for (int i = 0; i < 8; ++i)
      #pragma unroll
      for (int r = 0; r < 4; ++r) {
        const int t = m0 + wr * 128 + i * 16 + lg * 4 + r;
        #pragma unroll
        for (int j = 0; j < 4; ++j) {
          const int h = wc * 64 + j * 16 + lc;
          const float v = acc[i][j][r];
          kvout[(size_t)T_TOK * NKV * HD + ((size_t)t * NKV + kkh) * HD + h] = v;
          vb[((size_t)t * NKV + kkh) * HD + h] = f2bf(v);
        }
      }
    return;
  }

  // ---- Q/K: RMS row sums (block covers the full 256-wide head)
  #pragma unroll
  for (int i = 0; i < 8; ++i)
    #pragma unroll
    for (int r = 0; r < 4; ++r) {
      float s = acc[i][0][r] * acc[i][0][r] + acc[i][1][r] * acc[i][1][r]
              + acc[i][2][r] * acc[i][2][r] + acc[i][3][r] * acc[i][3][r];
      s += __shfl_xor(s, 1); s += __shfl_xor(s, 2);
      s += __shfl_xor(s, 4); s += __shfl_xor(s, 8);
      if (lc == 0) partial[wc][wr * 128 + i * 16 + lg * 4 + r] = s;
    }
  __syncthreads();
  if (tid < 256) {
    const float ss = partial[0][tid] + partial[1][tid] + partial[2][tid] + partial[3][tid];
    scl[tid] = rsqrtf(ss * (1.0f / 256.0f) + 1e-6f);
  }
  __syncthreads();

  const bool isq = (g < 8);
  const float qsc = isq ? 0.0625f : 1.0f;  // QUERY_PRE_ATTN_SCALAR^-0.5
  const float* wn = isq ? qnw : knw;
  float wnv[4];
  #pragma unroll
  for (int j = 0; j < 4; ++j) wnv[j] = wn[wc * 64 + j * 16 + lc] * qsc;
  #pragma unroll
  for (int i = 0; i < 8; ++i)
    #pragma unroll
    for (int r = 0; r < 4; ++r) {
      const float sc = scl[wr * 128 + i * 16 + lg * 4 + r];
      #pragma unroll
      for (int j = 0; j < 4; ++j) acc[i][j][r] *= sc * wnv[j];
    }

  // upper-half waves (cols 128..255) deposit f32 to LDS alias
  float* ldsF = (float*)&lds[0][0][0];  // 128KB, dead after main loop
  if (wc >= 2) {
    #pragma unroll
    for (int i = 0; i < 8; ++i)
      #pragma unroll
      for (int r = 0; r < 4; ++r) {
        const int row = wr * 128 + i * 16 + lg * 4 + r;
        #pragma unroll
        for (int j = 0; j < 4; ++j)
          ldsF[row * 128 + (wc - 2) * 64 + j * 16 + lc] = acc[i][j][r];
      }
  }
  __syncthreads();

  // lower-half waves compute BOTH roped outputs per pair
  if (wc < 2) {
    const float kf = 0.10381025296523007f;  // log2(10000)/128
    #pragma unroll
    for (int i = 0; i < 8; ++i)
      #pragma unroll
      for (int r = 0; r < 4; ++r) {
        const int row = wr * 128 + i * 16 + lg * 4 + r;
        const int t = m0 + row;
        const float p = (float)pos[t];
        #pragma unroll
        for (int j = 0; j < 4; ++j) {
          const int h = wc * 64 + j * 16 + lc;  // 0..127
          const float x1 = acc[i][j][r];
          const float x2 = ldsF[row * 128 + h];
          float sn, cs;
          sincosf(p * exp2f(-(float)h * kf), &sn, &cs);
          const float o1 = x1 * cs - x2 * sn;
          const float o2 = x2 * cs + x1 * sn;
          if (isq) {
            qb[(size_t)t * 2048 + g * 256 + h]       = f2bf(o1);
            qb[(size_t)t * 2048 + g * 256 + h + 128] = f2bf(o2);
          } else {
            const int kkh = g - 8;
            float* kf32 = kvout + ((size_t)t * NKV + kkh) * HD;
            kf32[h]       = o1;
            kf32[h + 128] = o2;
            u16* kb16 = kb + ((size_t)t * NKV + kkh) * HD;
            kb16[h]       = f2bf(o1);
            kb16[h + 128] = f2bf(o2);
          }
        }
      }
  }
}

// ---------------------------------------------------------------------------
// 128x320 bf16 GEMM, phase-interleaved progressive staging (o-projection).
__global__ __launch_bounds__(512, 1) void gemm_p2(
    const u16* __restrict__ A, const u16* __restrict__ B, float* __restrict__ C,
    int Kd, int lda, int ldb, int ldc)
{
  __shared__ __align__(16) u16 lds[2][(128 + 320) * 64];  // 114688 B
  const int tid = threadIdx.x;
  const int wave = tid >> 6, lane = tid & 63;
  const int lg = lane >> 4, lc = lane & 15;
  const int wr = wave >> 2, wc = wave & 3;
  const int nwg = gridDim.x, bid = blockIdx.x;
  const int nid = (bid & 7) * (nwg >> 3) + (bid >> 3);
  const int m0 = (nid & 31) * 128, n0 = (nid >> 5) * 320;
  const int NT = Kd >> 6;

  const int srow = tid >> 3;
  const int scol = ((tid & 7) * 16) ^ ((srow & 7) << 4);
  const u16* Ag = A + (size_t)(m0 + srow) * lda + (scol >> 1);
  const u16* Bg = B + (size_t)(n0 + srow) * ldb + (scol >> 1);

  #define STAGE_B5(BUF, KT) do {                                              \
    const int kc_ = (KT) * 64;                                                \
    _Pragma("unroll")                                                         \
    for (int li = 0; li < 5; ++li)                                            \
      async_cp16(Bg + (size_t)(li * 64) * ldb + kc_,                          \
                 (char*)&lds[BUF][0] + 16384 + li * 8192 + wave * 1024);      \
  } while (0)
  #define STAGE_A2P(BUF, KT) do {                                             \
    const int kc_ = (KT) * 64;                                                \
    _Pragma("unroll")                                                         \
    for (int li = 0; li < 2; ++li)                                            \
      async_cp16(Ag + (size_t)(li * 64) * lda + kc_,                          \
                 (char*)&lds[BUF][0] + li * 8192 + wave * 1024);              \
  } while (0)
  #define LOAD_AF2(P) do {                                                    \
    _Pragma("unroll")                                                         \
    for (int im = 0; im < 2; ++im)                                            \
      _Pragma("unroll")                                                       \
      for (int k2 = 0; k2 < 2; ++k2) {                                        \
        const int row = wr * 64 + ((P) * 2 + im) * 16 + lc;                   \
        const int cb = k2 * 64 + lg * 16;                                     \
        af[im][k2] = *(const bf16x8*)(Ab + row * 128 + (cb ^ ((row & 7) << 4))); \
      }                                                                       \
  } while (0)
  #define MFMA_Q2(P) do {                                                     \
    __builtin_amdgcn_s_setprio(1);                                            \
    _Pragma("unroll")                                                         \
    for (int im = 0; im < 2; ++im)                                            \
      _Pragma("unroll")                                                       \
      for (int j = 0; j < 5; ++j)                                             \
        _Pragma("unroll")                                                     \
        for (int k2 = 0; k2 < 2; ++k2)                                        \
          acc[(P) * 2 + im][j] = __builtin_amdgcn_mfma_f32_16x16x32_bf16(     \
              af[im][k2], bfr[j][k2], acc[(P) * 2 + im][j], 0, 0, 0);         \
    __builtin_amdgcn_s_setprio(0);                                            \
  } while (0)
  #define LGKM0_BAR2() do {                                                   \
    asm volatile("s_waitcnt lgkmcnt(0)" ::: "memory");                        \
    __builtin_amdgcn_s_barrier();                                             \
    __builtin_amdgcn_sched_barrier(0);                                        \
  } while (0)

  const f32x4 zf = {0.f, 0.f, 0.f, 0.f};
  f32x4 acc[4][5];
  #pragma unroll
  for (int i = 0; i < 4; ++i)
    #pragma unroll
    for (int j = 0; j < 5; ++j) acc[i][j] = zf;

  STAGE_B5(0, 0); STAGE_A2P(0, 0);
  STAGE_B5(1, 1); STAGE_A2P(1, 1);
  asm volatile("s_waitcnt vmcnt(7)" ::: "memory");
  __builtin_amdgcn_s_barrier();
  __builtin_amdgcn_sched_barrier(0);

  for (int t = 0; t < NT; ++t) {
    const int cur = t & 1;
    const char* Ab = (const char*)&lds[cur][0];
    const char* Bb = Ab + 16384;
    int nk = t + 2; if (nk > NT - 1) nk = NT - 1;

    bf16x8 bfr[5][2], af[2][2];
    #pragma unroll
    for (int j = 0; j < 5; ++j)
      #pragma unroll
      for (int k2 = 0; k2 < 2; ++k2) {
        const int row = wc * 80 + j * 16 + lc;
        const int cb = k2 * 64 + lg * 16;
        bfr[j][k2] = *(const bf16x8*)(Bb + row * 128 + (cb ^ ((row & 7) << 4)));
      }
    LOAD_AF2(0);
    LGKM0_BAR2();
    STAGE_B5(cur, nk);
    MFMA_Q2(0);
    LOAD_AF2(1);
    LGKM0_BAR2();
    STAGE_A2P(cur, nk);
    MFMA_Q2(1);
    asm volatile("s_waitcnt vmcnt(7)" ::: "memory");
    __builtin_amdgcn_s_barrier();
    __builtin_amdgcn_sched_barrier(0);
  }
  #undef STAGE_B5
  #undef STAGE_A2P
  #undef LOAD_AF2
  #undef MFMA_Q2
  #undef LGKM0_BAR2

  #pragma unroll
  for (int i = 0; i < 4; ++i)
    #pragma unroll
    for (int j = 0; j < 5; ++j)
      #pragma unroll
      for (int r = 0; r < 4; ++r) {
        const int row = m0 + wr * 64 + i * 16 + lg * 4 + r;
        const int col = n0 + wc * 80 + j * 16 + lc;
        C[(size_t)row * ldc + col] = acc[i][j][r];
      }
}

// ---------------------------------------------------------------------------
// Per-head V transpose: vb (T x NKV x HD bf16) -> vt (NKV x HD x T bf16).
__global__ __launch_bounds__(256) void transpose_v(
    const u16* __restrict__ vc, u16* __restrict__ vt)
{
  __shared__ u16 tile[64][72];
  const int kk = blockIdx.z;
  const int t0 = blockIdx.y * 64, h0 = blockIdx.x * 64;
  const int lr = threadIdx.x >> 3, ch = threadIdx.x & 7;
  #pragma unroll
  for (int h = 0; h < 2; ++h) {
    const int row = lr + h * 32;
    *(bf16x8*)&tile[row][ch * 8] =
        *(const bf16x8*)&vc[((size_t)(t0 + row) * NKV + kk) * HD + h0 + ch * 8];
  }
  __syncthreads();
  #pragma unroll
  for (int h = 0; h < 2; ++h) {
    const int hc = lr + h * 32;
    bf16x8 v;
    #pragma unroll
    for (int j = 0; j < 8; ++j) v[j] = (short)tile[ch * 8 + j][hc];
    *(bf16x8*)&vt[(size_t)kk * HD * T_TOK + (size_t)(h0 + hc) * T_TOK + t0 + ch * 8] = v;
  }
}

// ---------------------------------------------------------------------------
// Flash attention v5 + XCD-aware block mapping (r16 verified).
__global__ __launch_bounds__(512, 1) void attn_kernel(
    const u16* __restrict__ qb, const u16* __restrict__ kc,
    const u16* __restrict__ vt, u16* __restrict__ ob)
{
  __shared__ __align__(16) u16 Ks[2][64 * 256];    // [buf][key][d] swz
  __shared__ __align__(16) u16 Vts[2][256 * 64];   // [buf][d][key] swz
  __shared__ __align__(16) u16 Ps[8][16 * 64];     // per-wave [qrow][key] swz

  const int bid = blockIdx.x;
  const int xcd = bid & 7, idx = bid >> 3;
  const int kk = xcd >> 1;                       // kv head (2 XCDs per head)
  const int t0 = (idx + (xcd & 1) * 32) * 64;    // q-block (bijective over 64)
  const int tid = threadIdx.x;
  const int wave = tid >> 6, lane = tid & 63;
  const int lg = lane >> 4, lc = lane & 15;
  const int hq = kk * 2 + (wave >> 2);   // q head for this wave
  const int wrow = (wave & 3) * 16;      // q-row base within 64-row block
  const int lswz = (lc & 7) << 4;
  const f32x4 zf = {0.f, 0.f, 0.f, 0.f};

  const int lrowK = tid >> 5;                        // 0..15
  const int scolK = ((tid & 31) * 16) ^ ((lrowK & 7) << 4);
  const int lrowV = tid >> 3;                        // 0..63
  const int scolV = ((tid & 7) * 16) ^ ((lrowV & 7) << 4);

  #define STAGEKV(KT, BUF) do {                                                \
    const int kb_ = (KT) * 64;                                                 \
    const u16* kp_ = kc + (size_t)(kb_ + lrowK) * (NKV * HD) + kk * HD + (scolK >> 1); \
    _Pragma("unroll")                                                          \
    for (int is = 0; is < 4; ++is)                                             \
      async_cp16(kp_ + (size_t)(is * 16) * (NKV * HD),                         \
                 (char*)&Ks[BUF][0] + is * 8192 + wave * 1024);                \
    const u16* vp_ = vt + (size_t)kk * (HD * T_TOK) + (size_t)lrowV * T_TOK + kb_ + (scolV >> 1); \
    _Pragma("unroll")                                                          \
    for (int is = 0; is < 4; ++is)                                             \
      async_cp16(vp_ + (size_t)(is * 64) * T_TOK,                              \
                 (char*)&Vts[BUF][0] + is * 8192 + wave * 1024);               \
  } while (0)

  bf16x8 qf[8];
  {
    const u16* qp = qb + (size_t)(t0 + wrow + lc) * 2048 + hq * 256 + lg * 8;
    #pragma unroll
    for (int ks = 0; ks < 8; ++ks) qf[ks] = *(const bf16x8*)(qp + ks * 32);
  }

  f32x4 o_acc[16];
  #pragma unroll
  for (int j = 0; j < 16; ++j) o_acc[j] = zf;
  float m_r[4], l_r[4];
  #pragma unroll
  for (int r = 0; r < 4; ++r) { m_r[r] = -1e30f; l_r[r] = 0.f; }

  const int mtile = t0 >> 6;
  const int ktf = (mtile >= 16) ? (mtile - 16) : 0;

  STAGEKV(ktf, 0);
  __syncthreads();

  int cur = 0;
  for (int kt = ktf; kt <= mtile; ++kt) {
    const int kb = kt * 64;
    if (kt < mtile) STAGEKV(kt + 1, cur ^ 1);

    const u16* Kb = &Ks[cur][0];
    const u16* Vb = &Vts[cur][0];

    f32x4 sf[4];
    #pragma unroll
    for (int j = 0; j < 4; ++j) sf[j] = zf;
    __builtin_amdgcn_s_setprio(1);
    #pragma unroll
    for (int ks = 0; ks < 8; ++ks)
      #pragma unroll
      for (int j = 0; j < 4; ++j) {
        const int row = j * 16 + lc;
        bf16x8 kf = *(const bf16x8*)((const char*)Kb + ((row * 512 + ks * 64 + lg * 16) ^ lswz));
        sf[j] = __builtin_amdgcn_mfma_f32_16x16x32_bf16(qf[ks], kf, sf[j], 0, 0, 0);
      }
    __builtin_amdgcn_s_setprio(0);

    const bool interior = (kb >= t0 - 960) && (kb <= t0 - 64);
    if (!interior) {
      #pragma unroll
      for (int j = 0; j < 4; ++j) {
        const int gcol = kb + j * 16 + lc;
        #pragma unroll
        for (int r = 0; r < 4; ++r) {
          const int grow = t0 + wrow + lg * 4 + r;
          if ((unsigned)(grow - gcol) >= WIN) sf[j][r] = -1e30f;
        }
      }
    }

    float a_r[4];
    #pragma unroll
    for (int r = 0; r < 4; ++r) {
      float v = fmaxf(fmaxf(sf[0][r], sf[1][r]), fmaxf(sf[2][r], sf[3][r]));
      v = fmaxf(v, __shfl_xor(v, 1));
      v = fmaxf(v, __shfl_xor(v, 2));
      v = fmaxf(v, __shfl_xor(v, 4));
      v = fmaxf(v, __shfl_xor(v, 8));
      const float mn = fmaxf(m_r[r], v);
      a_r[r] = __expf(m_r[r] - mn);
      m_r[r] = mn;
    }

    char* myP = (char*)&Ps[wave][0];
    #pragma unroll
    for (int r = 0; r < 4; ++r) {
      const int row = lg * 4 + r;
      const int rsw = (row & 7) << 4;
      float su = 0.f;
      #pragma unroll
      for (int j = 0; j < 4; ++j) {
        const float p = __expf(sf[j][r] - m_r[r]);
        su += p;
        *(u16*)(myP + ((row * 128 + (j * 16 + lc) * 2) ^ rsw)) = f2bf(p);
      }
      su += __shfl_xor(su, 1);
      su += __shfl_xor(su, 2);
      su += __shfl_xor(su, 4);
      su += __shfl_xor(su, 8);
      l_r[r] = l_r[r] * a_r[r] + su;
    }

    #pragma unroll
    for (int j = 0; j < 16; ++j) {
      o_acc[j][0] *= a_r[0];
      o_acc[j][1] *= a_r[1];
      o_acc[j][2] *= a_r[2];
      o_acc[j][3] *= a_r[3];
    }

    bf16x8 pa[2];
    #pragma unroll
    for (int ks = 0; ks < 2; ++ks)
      pa[ks] = *(const bf16x8*)(myP + ((lc * 128 + ks * 64 + lg * 16) ^ lswz));
    __builtin_amdgcn_s_setprio(1);
    #pragma unroll
    for (int ks = 0; ks < 2; ++ks)
      #pragma unroll
      for (int j = 0; j < 16; ++j) {
        const int row = j * 16 + lc;
        bf16x8 vf = *(const bf16x8*)((const char*)Vb + ((row * 128 + ks * 64 + lg * 16) ^ lswz));
        o_acc[j] = __builtin_amdgcn_mfma_f32_16x16x32_bf16(pa[ks], vf, o_acc[j], 0, 0, 0);
      }
    __builtin_amdgcn_s_setprio(0);

    __syncthreads();
    cur ^= 1;
  }
  #undef STAGEKV

  #pragma unroll
  for (int r = 0; r < 4; ++r) {
    const float li = 1.f / l_r[r];
    const size_t rowb = (size_t)(t0 + wrow + lg * 4 + r) * 2048 + hq * 256 + lc;
    #pragma unroll
    for (int j = 0; j < 16; ++j)
      ob[rowb + j * 16] = f2bf(o_acc[j][r] * li);
  }
}

// ---------------------------------------------------------------------------
extern "C" void kernel_launch(void* const* d_in, const int* in_sizes, int n_in,
                              void* d_out, int out_size, void* d_ws, size_t ws_size,
                              hipStream_t stream)
{
  (void)in_sizes; (void)n_in; (void)out_size; (void)ws_size;
  const float* x   = (const float*)d_in[0];
  const float* wq  = (const float*)d_in[1];
  const float* wk  = (const float*)d_in[2];
  const float* wv  = (const float*)d_in[3];
  const float* wo  = (const float*)d_in[4];
  const float* qnw = (const float*)d_in[5];
  const float* knw = (const float*)d_in[6];
  const int*   pos = (const int*)d_in[7];
  float* out = (float*)d_out;  // f32: [2*T*NKV*HD kv cache][T*DM o]

  // workspace layout (peak 85,983,232 B), lifetime-aliased
  char* ws = (char*)d_ws;
  u16* woT   = (u16*)(ws);                    // 2560x2048 bf16 (10.5 MB), live to end
  u16* xb    = (u16*)(ws + 10485760);         // T x DM bf16 (21.0 MB)
  u16* wqkvT = (u16*)(ws + 31457280);         // 4096 x DM bf16 (21.0 MB)
  u16* q_b   = (u16*)(ws + 52428800);         // T x 2048 bf16 (16.8 MB)
  u16* kb    = (u16*)(ws + 69206016);         // T x NKV x HD bf16 (8.4 MB)
  u16* vb    = (u16*)(ws + 77594624);         // T x NKV x HD bf16 (8.4 MB)
  u16* vtb   = xb;                            // alias: xb dead after gemm_qkv (8.4 MB)
  u16* attn  = wqkvT;                         // alias: wqkvT dead after gemm_qkv (16.8 MB)

  // fused prelude: convert x + transpose wq/wk/wv/wo in one launch
  prelude<<<4864, 256, 0, stream>>>(x, wq, wk, wv, wo, xb, wqkvT, woT);

  // QKV projection + fused RMSNorm/scale/RoPE; k/v f32 -> kv cache (d_out)
  gemm_qkv<<<256, 512, 0, stream>>>(xb, wqkvT, qnw, knw, pos,
                                    q_b, kb, vb, out, DM, DM, DM);

  // V^T per head for PV MFMA B-operand
  transpose_v<<<dim3(4, 64, 4), 256, 0, stream>>>(vb, vtb);

  // flash attention: XCD-clustered 1D grid (256 blocks) -> attn (T x 2048)
  attn_kernel<<<256, 512, 0, stream>>>(q_b, kb, vtb, attn);

  // output projection: 128x320 tile, progressive schedule, 256 blocks
  gemm_p2<<<256, 512, 0, stream>>>(attn, woT, out + 2 * (size_t)T_TOK * NKV * HD,
                                   2048, 2048, 2048, DM);
}

// Round 19
// 239.072 us; speedup vs baseline: 1.2632x; 1.2632x over previous
//
#include <hip/hip_runtime.h>
#include <stdint.h>

// Problem constants (Gemma3 attention block)
#define T_TOK 4096
#define DM    2560
#define NQ    8
#define NKV   4
#define HD    256
#define WIN   1024

using bf16x8 = __attribute__((ext_vector_type(8))) short;
using f32x4  = __attribute__((ext_vector_type(4))) float;
typedef unsigned short u16;

__device__ __forceinline__ u16 f2bf(float x) {
  union { float f; uint32_t u; } v; v.f = x;
  uint32_t u = v.u;
  return (u16)((u + 0x7fffu + ((u >> 16) & 1u)) >> 16);  // RNE
}
__device__ __forceinline__ float bf2f(u16 b) {
  union { uint32_t u; float f; } v; v.u = ((uint32_t)b) << 16;
  return v.f;
}

// async global->LDS, 16B per lane. LDS dest is wave-uniform base; HW adds lane*16.
__device__ __forceinline__ void async_cp16(const void* g, void* lds) {
  __builtin_amdgcn_global_load_lds(
      (const __attribute__((address_space(1))) uint32_t*)(uintptr_t)g,
      (__attribute__((address_space(3))) uint32_t*)(uint32_t)(uintptr_t)lds,
      16, 0, 0);
}

// ---------------------------------------------------------------------------
// Fused prelude: one launch covering x->bf16 convert + 4 weight transposes.
// Block ranges: [0,1024) convert; [1024,2304) wq; [2304,2944) wk;
// [2944,3584) wv; [3584,4864) wo. Branch is block-uniform.
__global__ __launch_bounds__(256) void prelude(
    const float* __restrict__ x,  const float* __restrict__ wq,
    const float* __restrict__ wk, const float* __restrict__ wv,
    const float* __restrict__ wo,
    u16* __restrict__ xb, u16* __restrict__ wqkvT, u16* __restrict__ woT)
{
  __shared__ u16 tile[64][72];
  const int bid0 = blockIdx.x;

  if (bid0 < 1024) {
    // ---- convert x -> xb (8 elems/thread, 16B stores, grid-stride)
    for (int i = (bid0 * 256 + threadIdx.x) * 8; i < T_TOK * DM; i += 1024 * 256 * 8) {
      float4 a = *(const float4*)(x + i);
      float4 b = *(const float4*)(x + i + 4);
      bf16x8 o;
      o[0] = (short)f2bf(a.x); o[1] = (short)f2bf(a.y);
      o[2] = (short)f2bf(a.z); o[3] = (short)f2bf(a.w);
      o[4] = (short)f2bf(b.x); o[5] = (short)f2bf(b.y);
      o[6] = (short)f2bf(b.z); o[7] = (short)f2bf(b.w);
      *(bf16x8*)(xb + i) = o;
    }
    return;
  }

  // ---- transpose+convert: in f32 (R x C) -> out bf16 (C x R)
  const float* src; u16* dst; int R, C, bx, by;
  if (bid0 < 2304)      { int b = bid0 - 1024; src = wq; dst = wqkvT;             R = DM;   C = 2048; bx = b & 31; by = b >> 5; }
  else if (bid0 < 2944) { int b = bid0 - 2304; src = wk; dst = wqkvT + 2048 * DM; R = DM;   C = 1024; bx = b & 15; by = b >> 4; }
  else if (bid0 < 3584) { int b = bid0 - 2944; src = wv; dst = wqkvT + 3072 * DM; R = DM;   C = 1024; bx = b & 15; by = b >> 4; }
  else                  { int b = bid0 - 3584; src = wo; dst = woT;               R = 2048; C = DM;   bx = b % 40; by = b / 40; }

  const int r0 = by * 64, c0 = bx * 64;
  const int tr = threadIdx.x >> 6, tc = threadIdx.x & 63;
  #pragma unroll
  for (int i = 0; i < 16; ++i) {
    int r = tr + i * 4;
    tile[r][tc] = f2bf(src[(size_t)(r0 + r) * C + c0 + tc]);
  }
  __syncthreads();
  const int oc = threadIdx.x >> 3, ch = threadIdx.x & 7;
  #pragma unroll
  for (int h = 0; h < 2; ++h) {
    const int c = oc + h * 32;
    bf16x8 v;
    #pragma unroll
    for (int j = 0; j < 8; ++j) v[j] = (short)tile[ch * 8 + j][c];
    *(bf16x8*)(dst + (size_t)(c0 + c) * R + r0 + ch * 8) = v;
  }
}

// ---------------------------------------------------------------------------
// 256x256 bf16 GEMM, phase-interleaved progressive staging (round-12
// measured-best schedule: 86 us, MfmaUtil 41, 0 bank conflicts).
template<bool F32OUT>
__global__ __launch_bounds__(512, 1) void gemm256p(
    const u16* __restrict__ A, const u16* __restrict__ B, void* __restrict__ Cv,
    int Kd, int lda, int ldb, int ldc)
{
  __shared__ __align__(16) u16 lds[2][2][256 * 64];  // [buf][A|B] 128 KiB
  const int tid = threadIdx.x;
  const int wave = tid >> 6, lane = tid & 63;
  const int lg = lane >> 4, lc = lane & 15;
  const int wr = wave >> 2, wc = wave & 3;  // 2 x 4 wave grid
  const int nwg = gridDim.x, bid = blockIdx.x;
  const int nid = (bid & 7) * (nwg >> 3) + (bid >> 3);
  const int m0 = (nid & 15) * 256, n0 = (nid >> 4) * 256;
  const int NT = Kd >> 6;

  const int srow = tid >> 3;
  const int scol = ((tid & 7) * 16) ^ ((srow & 7) << 4);
  const u16* Ag = A + (size_t)(m0 + srow) * lda + (scol >> 1);
  const u16* Bg = B + (size_t)(n0 + srow) * ldb + (scol >> 1);

  #define STAGE_B4(BUF, KT) do {                                              \
    const int kc_ = (KT) * 64;                                                \
    _Pragma("unroll")                                                         \
    for (int li = 0; li < 4; ++li)                                            \
      async_cp16(Bg + (size_t)(li * 64) * ldb + kc_,                          \
                 (char*)&lds[BUF][1][0] + li * 8192 + wave * 1024);           \
  } while (0)
  #define STAGE_A2(BUF, KT, H) do {                                           \
    const int kc_ = (KT) * 64;                                                \
    async_cp16(Ag + (size_t)((H) * 64) * lda + kc_,                           \
               (char*)&lds[BUF][0][0] + (H) * 8192 + wave * 1024);            \
    async_cp16(Ag + (size_t)((H) * 64 + 128) * lda + kc_,                     \
               (char*)&lds[BUF][0][0] + ((H) + 2) * 8192 + wave * 1024);      \
  } while (0)
  #define LOAD_AF(P) do {                                                     \
    _Pragma("unroll")                                                         \
    for (int im = 0; im < 2; ++im)                                            \
      _Pragma("unroll")                                                       \
      for (int k2 = 0; k2 < 2; ++k2) {                                        \
        const int row = wr * 128 + ((P) * 2 + im) * 16 + lc;                  \
        const int cb = k2 * 64 + lg * 16;                                     \
        af[im][k2] = *(const bf16x8*)(Ab + row * 128 + (cb ^ ((row & 7) << 4))); \
      }                                                                       \
  } while (0)
  #define MFMA_Q(P) do {                                                      \
    __builtin_amdgcn_s_setprio(1);                                            \
    _Pragma("unroll")                                                         \
    for (int im = 0; im < 2; ++im)                                            \
      _Pragma("unroll")                                                       \
      for (int j = 0; j < 4; ++j)                                             \
        _Pragma("unroll")                                                     \
        for (int k2 = 0; k2 < 2; ++k2)                                        \
          acc[(P) * 2 + im][j] = __builtin_amdgcn_mfma_f32_16x16x32_bf16(     \
              af[im][k2], bfr[j][k2], acc[(P) * 2 + im][j], 0, 0, 0);         \
    __builtin_amdgcn_s_setprio(0);                                            \
  } while (0)
  #define LGKM0_BAR() do {                                                    \
    asm volatile("s_waitcnt lgkmcnt(0)" ::: "memory");                        \
    __builtin_amdgcn_s_barrier();                                             \
    __builtin_amdgcn_sched_barrier(0);                                        \
  } while (0)

  const f32x4 zf = {0.f, 0.f, 0.f, 0.f};
  f32x4 acc[8][4];
  #pragma unroll
  for (int i = 0; i < 8; ++i)
    #pragma unroll
    for (int j = 0; j < 4; ++j) acc[i][j] = zf;

  STAGE_B4(0, 0); STAGE_A2(0, 0, 0); STAGE_A2(0, 0, 1);
  STAGE_B4(1, 1); STAGE_A2(1, 1, 0); STAGE_A2(1, 1, 1);
  asm volatile("s_waitcnt vmcnt(8)" ::: "memory");
  __builtin_amdgcn_s_barrier();
  __builtin_amdgcn_sched_barrier(0);

  for (int t = 0; t < NT; ++t) {
    const int cur = t & 1;
    const char* Ab = (const char*)&lds[cur][0][0];
    const char* Bb = (const char*)&lds[cur][1][0];
    int nk = t + 2; if (nk > NT - 1) nk = NT - 1;

    bf16x8 bfr[4][2], af[2][2];
    #pragma unroll
    for (int j = 0; j < 4; ++j)
      #pragma unroll
      for (int k2 = 0; k2 < 2; ++k2) {
        const int row = wc * 64 + j * 16 + lc;
        const int cb = k2 * 64 + lg * 16;
        bfr[j][k2] = *(const bf16x8*)(Bb + row * 128 + (cb ^ ((row & 7) << 4)));
      }
    LOAD_AF(0);
    LGKM0_BAR();
    STAGE_B4(cur, nk);
    MFMA_Q(0);
    LOAD_AF(1);
    LGKM0_BAR();
    STAGE_A2(cur, nk, 0);
    MFMA_Q(1);
    LOAD_AF(2);
    MFMA_Q(2);
    LOAD_AF(3);
    LGKM0_BAR();
    STAGE_A2(cur, nk, 1);
    MFMA_Q(3);
    asm volatile("s_waitcnt vmcnt(8)" ::: "memory");
    __builtin_amdgcn_s_barrier();
    __builtin_amdgcn_sched_barrier(0);
  }
  #undef STAGE_B4
  #undef STAGE_A2
  #undef LOAD_AF
  #undef MFMA_Q
  #undef LGKM0_BAR

  #pragma unroll
  for (int i = 0; i < 8; ++i)
    #pragma unroll
    for (int j = 0; j < 4; ++j)
      #pragma unroll
      for (int r = 0; r < 4; ++r) {
        const int row = m0 + wr * 128 + i * 16 + lg * 4 + r;
        const int col = n0 + wc * 64 + j * 16 + lc;
        if (F32OUT) ((float*)Cv)[(size_t)row * ldc + col] = acc[i][j][r];
        else        ((u16*)Cv)[(size_t)row * ldc + col] = f2bf(acc[i][j][r]);
      }
}

// ---------------------------------------------------------------------------
// 128x320 bf16 GEMM, phase-interleaved progressive staging (o-projection).
__global__ __launch_bounds__(512, 1) void gemm_p2(
    const u16* __restrict__ A, const u16* __restrict__ B, float* __restrict__ C,
    int Kd, int lda, int ldb, int ldc)
{
  __shared__ __align__(16) u16 lds[2][(128 + 320) * 64];  // 114688 B
  const int tid = threadIdx.x;
  const int wave = tid >> 6, lane = tid & 63;
  const int lg = lane >> 4, lc = lane & 15;
  const int wr = wave >> 2, wc = wave & 3;
  const int nwg = gridDim.x, bid = blockIdx.x;
  const int nid = (bid & 7) * (nwg >> 3) + (bid >> 3);
  const int m0 = (nid & 31) * 128, n0 = (nid >> 5) * 320;
  const int NT = Kd >> 6;

  const int srow = tid >> 3;
  const int scol = ((tid & 7) * 16) ^ ((srow & 7) << 4);
  const u16* Ag = A + (size_t)(m0 + srow) * lda + (scol >> 1);
  const u16* Bg = B + (size_t)(n0 + srow) * ldb + (scol >> 1);

  #define STAGE_B5(BUF, KT) do {                                              \
    const int kc_ = (KT) * 64;                                                \
    _Pragma("unroll")                                                         \
    for (int li = 0; li < 5; ++li)                                            \
      async_cp16(Bg + (size_t)(li * 64) * ldb + kc_,                          \
                 (char*)&lds[BUF][0] + 16384 + li * 8192 + wave * 1024);      \
  } while (0)
  #define STAGE_A2P(BUF, KT) do {                                             \
    const int kc_ = (KT) * 64;                                                \
    _Pragma("unroll")                                                         \
    for (int li = 0; li < 2; ++li)                                            \
      async_cp16(Ag + (size_t)(li * 64) * lda + kc_,                          \
                 (char*)&lds[BUF][0] + li * 8192 + wave * 1024);              \
  } while (0)
  #define LOAD_AF2(P) do {                                                    \
    _Pragma("unroll")                                                         \
    for (int im = 0; im < 2; ++im)                                            \
      _Pragma("unroll")                                                       \
      for (int k2 = 0; k2 < 2; ++k2) {                                        \
        const int row = wr * 64 + ((P) * 2 + im) * 16 + lc;                   \
        const int cb = k2 * 64 + lg * 16;                                     \
        af[im][k2] = *(const bf16x8*)(Ab + row * 128 + (cb ^ ((row & 7) << 4))); \
      }                                                                       \
  } while (0)
  #define MFMA_Q2(P) do {                                                     \
    __builtin_amdgcn_s_setprio(1);                                            \
    _Pragma("unroll")                                                         \
    for (int im = 0; im < 2; ++im)                                            \
      _Pragma("unroll")                                                       \
      for (int j = 0; j < 5; ++j)                                             \
        _Pragma("unroll")                                                     \
        for (int k2 = 0; k2 < 2; ++k2)                                        \
          acc[(P) * 2 + im][j] = __builtin_amdgcn_mfma_f32_16x16x32_bf16(     \
              af[im][k2], bfr[j][k2], acc[(P) * 2 + im][j], 0, 0, 0);         \
    __builtin_amdgcn_s_setprio(0);                                            \
  } while (0)
  #define LGKM0_BAR2() do {                                                   \
    asm volatile("s_waitcnt lgkmcnt(0)" ::: "memory");                        \
    __builtin_amdgcn_s_barrier();                                             \
    __builtin_amdgcn_sched_barrier(0);                                        \
  } while (0)

  const f32x4 zf = {0.f, 0.f, 0.f, 0.f};
  f32x4 acc[4][5];
  #pragma unroll
  for (int i = 0; i < 4; ++i)
    #pragma unroll
    for (int j = 0; j < 5; ++j) acc[i][j] = zf;

  STAGE_B5(0, 0); STAGE_A2P(0, 0);
  STAGE_B5(1, 1); STAGE_A2P(1, 1);
  asm volatile("s_waitcnt vmcnt(7)" ::: "memory");
  __builtin_amdgcn_s_barrier();
  __builtin_amdgcn_sched_barrier(0);

  for (int t = 0; t < NT; ++t) {
    const int cur = t & 1;
    const char* Ab = (const char*)&lds[cur][0];
    const char* Bb = Ab + 16384;
    int nk = t + 2; if (nk > NT - 1) nk = NT - 1;

    bf16x8 bfr[5][2], af[2][2];
    #pragma unroll
    for (int j = 0; j < 5; ++j)
      #pragma unroll
      for (int k2 = 0; k2 < 2; ++k2) {
        const int row = wc * 80 + j * 16 + lc;
        const int cb = k2 * 64 + lg * 16;
        bfr[j][k2] = *(const bf16x8*)(Bb + row * 128 + (cb ^ ((row & 7) << 4)));
      }
    LOAD_AF2(0);
    LGKM0_BAR2();
    STAGE_B5(cur, nk);
    MFMA_Q2(0);
    LOAD_AF2(1);
    LGKM0_BAR2();
    STAGE_A2P(cur, nk);
    MFMA_Q2(1);
    asm volatile("s_waitcnt vmcnt(7)" ::: "memory");
    __builtin_amdgcn_s_barrier();
    __builtin_amdgcn_sched_barrier(0);
  }
  #undef STAGE_B5
  #undef STAGE_A2P
  #undef LOAD_AF2
  #undef MFMA_Q2
  #undef LGKM0_BAR2

  #pragma unroll
  for (int i = 0; i < 4; ++i)
    #pragma unroll
    for (int j = 0; j < 5; ++j)
      #pragma unroll
      for (int r = 0; r < 4; ++r) {
        const int row = m0 + wr * 64 + i * 16 + lg * 4 + r;
        const int col = n0 + wc * 80 + j * 16 + lc;
        C[(size_t)row * ldc + col] = acc[i][j][r];
      }
}

// ---------------------------------------------------------------------------
// Fused RMSNorm + query-scale + RoPE. Reads qkv (T x 4096 bf16):
// cols [0,2048) = q (n-major), [2048,3072) = k, [3072,4096) = v.
__global__ __launch_bounds__(256) void fuse_norm_rope(
    const u16* __restrict__ qkv, const float* __restrict__ qnw, const float* __restrict__ knw,
    const int* __restrict__ pos, u16* __restrict__ qb, u16* __restrict__ kb,
    u16* __restrict__ vb, float* __restrict__ kvout)
{
  const int t = blockIdx.x;
  const int wave = threadIdx.x >> 6, lane = threadIdx.x & 63;
  const float p = (float)pos[t];
  const float kf = 0.10381025296523007f;  // log2(10000)/128
  float s0, c0, s1, c1;
  sincosf(p * exp2f(-(float)lane * kf), &s0, &c0);
  sincosf(p * exp2f(-(float)(lane + 64) * kf), &s1, &c1);
  const u16* row = qkv + (size_t)t * 4096;

  for (int pp = 0; pp < 4; ++pp) {
    const int hr = pp * 4 + wave;  // 0..7 q, 8..11 k, 12..15 v
    if (hr >= 12) {
      const int kk = hr - 12;
      const u16* src = row + 3072 + kk * 256;
      float* dstf = kvout + (size_t)T_TOK * NKV * HD + ((size_t)t * NKV + kk) * HD;
      u16*   dstb = vb + ((size_t)t * NKV + kk) * HD;
      #pragma unroll
      for (int q4 = 0; q4 < 4; ++q4) {
        const u16 s = src[lane + q4 * 64];
        dstf[lane + q4 * 64] = bf2f(s);
        dstb[lane + q4 * 64] = s;
      }
    } else {
      const bool isq = hr < 8;
      const int cb = isq ? hr * 256 : 2048 + (hr - 8) * 256;
      float v0 = bf2f(row[cb + lane]);
      float v1 = bf2f(row[cb + lane + 64]);
      float v2 = bf2f(row[cb + lane + 128]);
      float v3 = bf2f(row[cb + lane + 192]);
      float ss = v0 * v0 + v1 * v1 + v2 * v2 + v3 * v3;
      #pragma unroll
      for (int off = 1; off < 64; off <<= 1) ss += __shfl_xor(ss, off);
      float sc = rsqrtf(ss * (1.0f / 256.0f) + 1e-6f);
      if (isq) sc *= 0.0625f;  // QUERY_PRE_ATTN_SCALAR^-0.5
      const float* wn = isq ? qnw : knw;
      v0 *= sc * wn[lane];
      v1 *= sc * wn[lane + 64];
      v2 *= sc * wn[lane + 128];
      v3 *= sc * wn[lane + 192];
      const float n0 = v0 * c0 - v2 * s0;
      const float n2 = v2 * c0 + v0 * s0;
      const float n1 = v1 * c1 - v3 * s1;
      const float n3 = v3 * c1 + v1 * s1;
      if (isq) {
        u16* dst = qb + (size_t)t * 2048 + hr * 256;
        dst[lane]       = f2bf(n0);
        dst[lane + 64]  = f2bf(n1);
        dst[lane + 128] = f2bf(n2);
        dst[lane + 192] = f2bf(n3);
      } else {
        const int kk = hr - 8;
        float* dstf = kvout + ((size_t)t * NKV + kk) * HD;
        dstf[lane]       = n0;
        dstf[lane + 64]  = n1;
        dstf[lane + 128] = n2;
        dstf[lane + 192] = n3;
        u16* dstb = kb + ((size_t)t * NKV + kk) * HD;
        dstb[lane]       = f2bf(n0);
        dstb[lane + 64]  = f2bf(n1);
        dstb[lane + 128] = f2bf(n2);
        dstb[lane + 192] = f2bf(n3);
      }
    }
  }
}

// ---------------------------------------------------------------------------
// Per-head V transpose: vb (T x NKV x HD bf16) -> vt (NKV x HD x T bf16).
__global__ __launch_bounds__(256) void transpose_v(
    const u16* __restrict__ vc, u16* __restrict__ vt)
{
  __shared__ u16 tile[64][72];
  const int kk = blockIdx.z;
  const int t0 = blockIdx.y * 64, h0 = blockIdx.x * 64;
  const int lr = threadIdx.x >> 3, ch = threadIdx.x & 7;
  #pragma unroll
  for (int h = 0; h < 2; ++h) {
    const int row = lr + h * 32;
    *(bf16x8*)&tile[row][ch * 8] =
        *(const bf16x8*)&vc[((size_t)(t0 + row) * NKV + kk) * HD + h0 + ch * 8];
  }
  __syncthreads();
  #pragma unroll
  for (int h = 0; h < 2; ++h) {
    const int hc = lr + h * 32;
    bf16x8 v;
    #pragma unroll
    for (int j = 0; j < 8; ++j) v[j] = (short)tile[ch * 8 + j][hc];
    *(bf16x8*)&vt[(size_t)kk * HD * T_TOK + (size_t)(h0 + hc) * T_TOK + t0 + ch * 8] = v;
  }
}

// ---------------------------------------------------------------------------
// Flash attention v5 + XCD-aware block mapping (r16 verified).
__global__ __launch_bounds__(512, 1) void attn_kernel(
    const u16* __restrict__ qb, const u16* __restrict__ kc,
    const u16* __restrict__ vt, u16* __restrict__ ob)
{
  __shared__ __align__(16) u16 Ks[2][64 * 256];    // [buf][key][d] swz
  __shared__ __align__(16) u16 Vts[2][256 * 64];   // [buf][d][key] swz
  __shared__ __align__(16) u16 Ps[8][16 * 64];     // per-wave [qrow][key] swz

  const int bid = blockIdx.x;
  const int xcd = bid & 7, idx = bid >> 3;
  const int kk = xcd >> 1;                       // kv head (2 XCDs per head)
  const int t0 = (idx + (xcd & 1) * 32) * 64;    // q-block (bijective over 64)
  const int tid = threadIdx.x;
  const int wave = tid >> 6, lane = tid & 63;
  const int lg = lane >> 4, lc = lane & 15;
  const int hq = kk * 2 + (wave >> 2);   // q head for this wave
  const int wrow = (wave & 3) * 16;      // q-row base within 64-row block
  const int lswz = (lc & 7) << 4;
  const f32x4 zf = {0.f, 0.f, 0.f, 0.f};

  const int lrowK = tid >> 5;                        // 0..15
  const int scolK = ((tid & 31) * 16) ^ ((lrowK & 7) << 4);
  const int lrowV = tid >> 3;                        // 0..63
  const int scolV = ((tid & 7) * 16) ^ ((lrowV & 7) << 4);

  #define STAGEKV(KT, BUF) do {                                                \
    const int kb_ = (KT) * 64;                                                 \
    const u16* kp_ = kc + (size_t)(kb_ + lrowK) * (NKV * HD) + kk * HD + (scolK >> 1); \
    _Pragma("unroll")                                                          \
    for (int is = 0; is < 4; ++is)                                             \
      async_cp16(kp_ + (size_t)(is * 16) * (NKV * HD),                         \
                 (char*)&Ks[BUF][0] + is * 8192 + wave * 1024);                \
    const u16* vp_ = vt + (size_t)kk * (HD * T_TOK) + (size_t)lrowV * T_TOK + kb_ + (scolV >> 1); \
    _Pragma("unroll")                                                          \
    for (int is = 0; is < 4; ++is)                                             \
      async_cp16(vp_ + (size_t)(is * 64) * T_TOK,                              \
                 (char*)&Vts[BUF][0] + is * 8192 + wave * 1024);               \
  } while (0)

  bf16x8 qf[8];
  {
    const u16* qp = qb + (size_t)(t0 + wrow + lc) * 2048 + hq * 256 + lg * 8;
    #pragma unroll
    for (int ks = 0; ks < 8; ++ks) qf[ks] = *(const bf16x8*)(qp + ks * 32);
  }

  f32x4 o_acc[16];
  #pragma unroll
  for (int j = 0; j < 16; ++j) o_acc[j] = zf;
  float m_r[4], l_r[4];
  #pragma unroll
  for (int r = 0; r < 4; ++r) { m_r[r] = -1e30f; l_r[r] = 0.f; }

  const int mtile = t0 >> 6;
  const int ktf = (mtile >= 16) ? (mtile - 16) : 0;

  STAGEKV(ktf, 0);
  __syncthreads();

  int cur = 0;
  for (int kt = ktf; kt <= mtile; ++kt) {
    const int kb = kt * 64;
    if (kt < mtile) STAGEKV(kt + 1, cur ^ 1);

    const u16* Kb = &Ks[cur][0];
    const u16* Vb = &Vts[cur][0];

    f32x4 sf[4];
    #pragma unroll
    for (int j = 0; j < 4; ++j) sf[j] = zf;
    __builtin_amdgcn_s_setprio(1);
    #pragma unroll
    for (int ks = 0; ks < 8; ++ks)
      #pragma unroll
      for (int j = 0; j < 4; ++j) {
        const int row = j * 16 + lc;
        bf16x8 kf = *(const bf16x8*)((const char*)Kb + ((row * 512 + ks * 64 + lg * 16) ^ lswz));
        sf[j] = __builtin_amdgcn_mfma_f32_16x16x32_bf16(qf[ks], kf, sf[j], 0, 0, 0);
      }
    __builtin_amdgcn_s_setprio(0);

    const bool interior = (kb >= t0 - 960) && (kb <= t0 - 64);
    if (!interior) {
      #pragma unroll
      for (int j = 0; j < 4; ++j) {
        const int gcol = kb + j * 16 + lc;
        #pragma unroll
        for (int r = 0; r < 4; ++r) {
          const int grow = t0 + wrow + lg * 4 + r;
          if ((unsigned)(grow - gcol) >= WIN) sf[j][r] = -1e30f;
        }
      }
    }

    float a_r[4];
    #pragma unroll
    for (int r = 0; r < 4; ++r) {
      float v = fmaxf(fmaxf(sf[0][r], sf[1][r]), fmaxf(sf[2][r], sf[3][r]));
      v = fmaxf(v, __shfl_xor(v, 1));
      v = fmaxf(v, __shfl_xor(v, 2));
      v = fmaxf(v, __shfl_xor(v, 4));
      v = fmaxf(v, __shfl_xor(v, 8));
      const float mn = fmaxf(m_r[r], v);
      a_r[r] = __expf(m_r[r] - mn);
      m_r[r] = mn;
    }

    char* myP = (char*)&Ps[wave][0];
    #pragma unroll
    for (int r = 0; r < 4; ++r) {
      const int row = lg * 4 + r;
      const int rsw = (row & 7) << 4;
      float su = 0.f;
      #pragma unroll
      for (int j = 0; j < 4; ++j) {
        const float p = __expf(sf[j][r] - m_r[r]);
        su += p;
        *(u16*)(myP + ((row * 128 + (j * 16 + lc) * 2) ^ rsw)) = f2bf(p);
      }
      su += __shfl_xor(su, 1);
      su += __shfl_xor(su, 2);
      su += __shfl_xor(su, 4);
      su += __shfl_xor(su, 8);
      l_r[r] = l_r[r] * a_r[r] + su;
    }

    #pragma unroll
    for (int j = 0; j < 16; ++j) {
      o_acc[j][0] *= a_r[0];
      o_acc[j][1] *= a_r[1];
      o_acc[j][2] *= a_r[2];
      o_acc[j][3] *= a_r[3];
    }

    bf16x8 pa[2];
    #pragma unroll
    for (int ks = 0; ks < 2; ++ks)
      pa[ks] = *(const bf16x8*)(myP + ((lc * 128 + ks * 64 + lg * 16) ^ lswz));
    __builtin_amdgcn_s_setprio(1);
    #pragma unroll
    for (int ks = 0; ks < 2; ++ks)
      #pragma unroll
      for (int j = 0; j < 16; ++j) {
        const int row = j * 16 + lc;
        bf16x8 vf = *(const bf16x8*)((const char*)Vb + ((row * 128 + ks * 64 + lg * 16) ^ lswz));
        o_acc[j] = __builtin_amdgcn_mfma_f32_16x16x32_bf16(pa[ks], vf, o_acc[j], 0, 0, 0);
      }
    __builtin_amdgcn_s_setprio(0);

    __syncthreads();
    cur ^= 1;
  }
  #undef STAGEKV

  #pragma unroll
  for (int r = 0; r < 4; ++r) {
    const float li = 1.f / l_r[r];
    const size_t rowb = (size_t)(t0 + wrow + lg * 4 + r) * 2048 + hq * 256 + lc;
    #pragma unroll
    for (int j = 0; j < 16; ++j)
      ob[rowb + j * 16] = f2bf(o_acc[j][r] * li);
  }
}

// ---------------------------------------------------------------------------
extern "C" void kernel_launch(void* const* d_in, const int* in_sizes, int n_in,
                              void* d_out, int out_size, void* d_ws, size_t ws_size,
                              hipStream_t stream)
{
  (void)in_sizes; (void)n_in; (void)out_size; (void)ws_size;
  const float* x   = (const float*)d_in[0];
  const float* wq  = (const float*)d_in[1];
  const float* wk  = (const float*)d_in[2];
  const float* wv  = (const float*)d_in[3];
  const float* wo  = (const float*)d_in[4];
  const float* qnw = (const float*)d_in[5];
  const float* knw = (const float*)d_in[6];
  const int*   pos = (const int*)d_in[7];
  float* out = (float*)d_out;  // f32: [2*T*NKV*HD kv cache][T*DM o]

  // workspace layout (peak 86 MB), lifetime-aliased
  char* ws = (char*)d_ws;
  u16* woT   = (u16*)(ws);                    // 2560x2048 bf16 (10.5 MB), live to end
  u16* xb    = (u16*)(ws + 10485760);         // T x DM bf16 (21.0 MB)
  u16* wqkvT = (u16*)(ws + 31457280);         // 4096 x DM bf16 (21.0 MB)
  u16* qkv   = (u16*)(ws + 52428800);         // T x 4096 bf16 (33.6 MB)
  u16* q_b   = xb;                            // alias: xb dead after gemm1 (16.8 MB)
  u16* kb    = wqkvT;                         // alias: wqkvT dead after gemm1 (8.4 MB)
  u16* vb    = (u16*)(ws + 31457280 + 8388608); // (8.4 MB, still inside wqkvT)
  u16* vtb   = qkv;                           // alias: qkv dead after fuse (8.4 MB)
  u16* attn  = (u16*)(ws + 52428800 + 8388608); // (16.8 MB, inside qkv region)

  // fused prelude: convert x + transpose wq/wk/wv/wo in one launch
  prelude<<<4864, 256, 0, stream>>>(x, wq, wk, wv, wo, xb, wqkvT, woT);

  // QKV projection: 256x256 tile, progressive schedule (r12 best), 256 blocks
  gemm256p<false><<<256, 512, 0, stream>>>(xb, wqkvT, qkv, DM, DM, DM, 4096);

  // RMSNorm + scale + RoPE; k/v f32 into kv cache (d_out) + bf16 copies
  fuse_norm_rope<<<T_TOK, 256, 0, stream>>>(qkv, qnw, knw, pos, q_b, kb, vb, out);

  // V^T per head for PV MFMA B-operand
  transpose_v<<<dim3(4, 64, 4), 256, 0, stream>>>(vb, vtb);

  // flash attention: XCD-clustered 1D grid (256 blocks) -> attn (T x 2048)
  attn_kernel<<<256, 512, 0, stream>>>(q_b, kb, vtb, attn);

  // output projection: 128x320 tile, progressive schedule, 256 blocks
  gemm_p2<<<256, 512, 0, stream>>>(attn, woT, out + 2 * (size_t)T_TOK * NKV * HD,
                                   2048, 2048, 2048, DM);
}